// Round 5
// baseline (128.160 us; speedup 1.0000x reference)
//
#include <hip/hip_runtime.h>
#include <math.h>

#define N_ROWS 32768
#define K_CODES 4096
#define DIM 64
#define TILES_TOTAL (K_CODES / 32)   // 128
#define TILES_PER_WAVE (TILES_TOTAL / 4)  // 32
#define QUANT_ELEMS (N_ROWS * DIM)   // 2097152

typedef _Float16 half8 __attribute__((ext_vector_type(8)));
typedef float floatx16 __attribute__((ext_vector_type(16)));

#define MFMA32(a, b, c) __builtin_amdgcn_mfma_f32_32x32x16_f16((a), (b), (c), 0, 0, 0)

// ---------------------------------------------------------------------------
// Kernel 0 (fused): embed -> fp16 hi/lo B-fragments for mfma_f32_32x32x16_f16
// AND per-code squared norms (LDS reduction).
// Tile c = 32 codes; kstep s covers k=16s..16s+15. Thread t = c*256 + s*64 + l
// holds B[k=(l>>5)*8+j+16s][col=l&31] = embed[c*32+(l&31)][(l>>5)*8+j+16s].
// One 256-thread block per tile (grid = 128 blocks).
// ---------------------------------------------------------------------------
__global__ void prep_kernel(const float* __restrict__ embed,
                            float* __restrict__ sq, half8* __restrict__ ehi,
                            half8* __restrict__ elo) {
    __shared__ float part[256];
    const int tid = threadIdx.x;
    const int t = blockIdx.x * 256 + tid;
    const int l = t & 63;
    const int s = (t >> 6) & 3;
    const int c = blockIdx.x;
    const int col = l & 31;
    const int code = c * 32 + col;
    const int koff = (l >> 5) * 8 + 16 * s;
    const float* src = embed + (size_t)code * DIM + koff;
    half8 h, lo;
    float ss = 0.f;
#pragma unroll
    for (int j = 0; j < 8; ++j) {
        float v = src[j];
        ss = fmaf(v, v, ss);
        _Float16 hi = (_Float16)v;
        h[j] = hi;
        lo[j] = (_Float16)(v - (float)hi);
    }
    ehi[t] = h;
    elo[t] = lo;
    part[tid] = ss;
    __syncthreads();
    if (tid < 32) {
        float a = 0.f;
#pragma unroll
        for (int q = 0; q < 8; ++q)
            a += part[tid + 32 * (q & 1) + 64 * (q >> 1)];
        sq[c * 32 + tid] = a;
    }
}

// ---------------------------------------------------------------------------
// Kernel 1: fully fused dist(GEMM 32x32x16) + argmax + combine + gather.
// Block = 4 waves over the SAME 64 rows; wave w sweeps tiles
// [w*32, (w+1)*32) with B streamed L2->registers (no LDS in hot loop).
// M=64 rows/wave: 24 MFMA per 8 KB B-tile. Epilogue: 32-lane butterfly,
// cross-wave LDS reduce (ascending code ranges => strict > keeps earliest),
// gather embed rows, write quantize + index-as-float.
// dist = dot(2x,e) - ||e||^2 ; -||e||^2 = acc init, 2x folded into A (exact).
// fp16 split, 3 terms: xh*eh + xl*eh + xh*el.
// grid = 512 blocks (= 2 blocks/CU, 8 waves/CU), block = 256.
// ---------------------------------------------------------------------------
__global__ __launch_bounds__(256, 2) void fused_all(
    const float* __restrict__ x, const float* __restrict__ sq,
    const half8* __restrict__ ehi, const half8* __restrict__ elo,
    const float* __restrict__ embed, float* __restrict__ out) {
    __shared__ float rbest[4][64];
    __shared__ int ridx[4][64];
    __shared__ int fidx[64];

    const int tid = threadIdx.x;
    const int lane = tid & 63;
    const int wave = tid >> 6;
    const int col = lane & 31;    // B col (code within tile); A row
    const int half_ = lane >> 5;  // k-half
    const int row_base = blockIdx.x * 64;

    // Persistent A fragments, two 32-row subtiles, scaled by 2 (exact).
    // A[m=col (+32*m)][k = half_*8 + j + 16*s]
    half8 ah[2][4], al[2][4];
#pragma unroll
    for (int m = 0; m < 2; ++m) {
        const float* xs =
            x + (size_t)(row_base + m * 32 + col) * DIM + half_ * 8;
#pragma unroll
        for (int s = 0; s < 4; ++s) {
            half8 h, lo;
#pragma unroll
            for (int j = 0; j < 8; ++j) {
                float v = 2.0f * xs[16 * s + j];
                _Float16 hi = (_Float16)v;
                h[j] = hi;
                lo[j] = (_Float16)(v - (float)hi);
            }
            ah[m][s] = h;
            al[m][s] = lo;
        }
    }

    float best0[16], best1[16];
    int idx0[16], idx1[16];
#pragma unroll
    for (int r = 0; r < 16; ++r) {
        best0[r] = -INFINITY;
        best1[r] = -INFINITY;
        idx0[r] = 0;
        idx1[r] = 0;
    }

    const int c0 = wave * TILES_PER_WAVE;
    const half8* ph = ehi + (size_t)c0 * 256 + lane;
    const half8* pl = elo + (size_t)c0 * 256 + lane;
    const float* psq = sq + c0 * 32 + col;

    for (int c = 0; c < TILES_PER_WAVE; ++c) {
        half8 bh0 = ph[0], bh1 = ph[64], bh2 = ph[128], bh3 = ph[192];
        half8 bl0 = pl[0], bl1 = pl[64], bl2 = pl[128], bl3 = pl[192];
        float nsq = -psq[0];
        ph += 256;
        pl += 256;
        psq += 32;

        floatx16 acc0, acc1;
#pragma unroll
        for (int r = 0; r < 16; ++r) {
            acc0[r] = nsq;
            acc1[r] = nsq;
        }
        // kstep 0
        acc0 = MFMA32(ah[0][0], bh0, acc0);
        acc1 = MFMA32(ah[1][0], bh0, acc1);
        acc0 = MFMA32(al[0][0], bh0, acc0);
        acc1 = MFMA32(al[1][0], bh0, acc1);
        acc0 = MFMA32(ah[0][0], bl0, acc0);
        acc1 = MFMA32(ah[1][0], bl0, acc1);
        // kstep 1
        acc0 = MFMA32(ah[0][1], bh1, acc0);
        acc1 = MFMA32(ah[1][1], bh1, acc1);
        acc0 = MFMA32(al[0][1], bh1, acc0);
        acc1 = MFMA32(al[1][1], bh1, acc1);
        acc0 = MFMA32(ah[0][1], bl1, acc0);
        acc1 = MFMA32(ah[1][1], bl1, acc1);
        // kstep 2
        acc0 = MFMA32(ah[0][2], bh2, acc0);
        acc1 = MFMA32(ah[1][2], bh2, acc1);
        acc0 = MFMA32(al[0][2], bh2, acc0);
        acc1 = MFMA32(al[1][2], bh2, acc1);
        acc0 = MFMA32(ah[0][2], bl2, acc0);
        acc1 = MFMA32(ah[1][2], bl2, acc1);
        // kstep 3
        acc0 = MFMA32(ah[0][3], bh3, acc0);
        acc1 = MFMA32(ah[1][3], bh3, acc1);
        acc0 = MFMA32(al[0][3], bh3, acc0);
        acc1 = MFMA32(al[1][3], bh3, acc1);
        acc0 = MFMA32(ah[0][3], bl3, acc0);
        acc1 = MFMA32(ah[1][3], bl3, acc1);

        const int cidx = (c0 + c) * 32 + col;
#pragma unroll
        for (int r = 0; r < 16; ++r) {
            if (acc0[r] > best0[r]) {  // strict >: earliest tile wins ties
                best0[r] = acc0[r];
                idx0[r] = cidx;
            }
            if (acc1[r] > best1[r]) {
                best1[r] = acc1[r];
                idx1[r] = cidx;
            }
        }
    }

    // C/D layout (32x32): col = lane&31, row = (r&3) + 8*(r>>2) + 4*half_.
    // Butterfly over the 32 lanes of each half (cols), then stash per-wave
    // winners in LDS.
#pragma unroll
    for (int r = 0; r < 16; ++r) {
        const int row = (r & 3) + 8 * (r >> 2) + 4 * half_;
        float bv = best0[r];
        int bi = idx0[r];
#pragma unroll
        for (int d = 1; d < 32; d <<= 1) {
            float ov = __shfl_xor(bv, d);
            int oi = __shfl_xor(bi, d);
            if (ov > bv || (ov == bv && oi < bi)) {  // smaller idx on tie
                bv = ov;
                bi = oi;
            }
        }
        if (col == 0) {
            rbest[wave][row] = bv;
            ridx[wave][row] = bi;
        }
        bv = best1[r];
        bi = idx1[r];
#pragma unroll
        for (int d = 1; d < 32; d <<= 1) {
            float ov = __shfl_xor(bv, d);
            int oi = __shfl_xor(bi, d);
            if (ov > bv || (ov == bv && oi < bi)) {
                bv = ov;
                bi = oi;
            }
        }
        if (col == 0) {
            rbest[wave][row + 32] = bv;
            ridx[wave][row + 32] = bi;
        }
    }
    __syncthreads();

    // Cross-wave combine: wave order == ascending code ranges, so strict >
    // preserves jnp.argmax first-max semantics.
    if (tid < 64) {
        float bv = rbest[0][tid];
        int bi = ridx[0][tid];
#pragma unroll
        for (int w = 1; w < 4; ++w) {
            float b = rbest[w][tid];
            if (b > bv) {
                bv = b;
                bi = ridx[w][tid];
            }
        }
        fidx[tid] = bi;
        out[(size_t)QUANT_ELEMS + row_base + tid] = (float)bi;
    }
    __syncthreads();

    // Gather + write quantize: 256 threads x 4 float4 chunks = 64 rows x 64f.
    const int grow = tid >> 2;
    const int q0 = tid & 3;
    const int bi = fidx[grow];
    const float4* e4 = reinterpret_cast<const float4*>(embed);
    float4* o4 = reinterpret_cast<float4*>(out);
#pragma unroll
    for (int q = 0; q < 4; ++q) {
        const int chunk = q0 + 4 * q;
        o4[(size_t)(row_base + grow) * (DIM / 4) + chunk] =
            e4[(size_t)bi * (DIM / 4) + chunk];
    }
}

// ---------------------------------------------------------------------------
extern "C" void kernel_launch(void* const* d_in, const int* in_sizes, int n_in,
                              void* d_out, int out_size, void* d_ws,
                              size_t ws_size, hipStream_t stream) {
    const float* x = (const float*)d_in[0];
    const float* embed = (const float*)d_in[1];
    float* out = (float*)d_out;

    // ws: sq 16KB | ehi 512KB | elo 512KB
    char* ws = (char*)d_ws;
    float* sq = (float*)ws;
    half8* ehi = (half8*)(ws + 16384);
    half8* elo = (half8*)(ws + 16384 + 524288);

    prep_kernel<<<TILES_TOTAL, 256, 0, stream>>>(embed, sq, ehi, elo);

    fused_all<<<N_ROWS / 64, 256, 0, stream>>>(x, sq, ehi, elo, embed, out);
}

// Round 6
// 123.726 us; speedup vs baseline: 1.0358x; 1.0358x over previous
//
#include <hip/hip_runtime.h>
#include <math.h>

#define N_ROWS 32768
#define K_CODES 4096
#define DIM 64
#define TILES_TOTAL (K_CODES / 32)        // 128
#define TILES_PER_WAVE (TILES_TOTAL / 4)  // 32
#define QUANT_ELEMS (N_ROWS * DIM)        // 2097152

typedef _Float16 half8 __attribute__((ext_vector_type(8)));
typedef float floatx16 __attribute__((ext_vector_type(16)));

#define MFMA32(a, b, c) __builtin_amdgcn_mfma_f32_32x32x16_f16((a), (b), (c), 0, 0, 0)

// ---------------------------------------------------------------------------
// Kernel 0 (fused): embed -> fp16 hi/lo B-fragments for mfma_f32_32x32x16_f16
// AND per-code squared norms (LDS reduction).
// Tile c = 32 codes; kstep s covers k=16s..16s+15. Thread t = c*256 + s*64 + l
// holds B[k=(l>>5)*8+j+16s][col=l&31] = embed[c*32+(l&31)][(l>>5)*8+j+16s].
// One 256-thread block per tile (grid = 128 blocks).
// ---------------------------------------------------------------------------
__global__ void prep_kernel(const float* __restrict__ embed,
                            float* __restrict__ sq, half8* __restrict__ ehi,
                            half8* __restrict__ elo) {
    __shared__ float part[256];
    const int tid = threadIdx.x;
    const int t = blockIdx.x * 256 + tid;
    const int l = t & 63;
    const int s = (t >> 6) & 3;
    const int c = blockIdx.x;
    const int col = l & 31;
    const int code = c * 32 + col;
    const int koff = (l >> 5) * 8 + 16 * s;
    const float* src = embed + (size_t)code * DIM + koff;
    half8 h, lo;
    float ss = 0.f;
#pragma unroll
    for (int j = 0; j < 8; ++j) {
        float v = src[j];
        ss = fmaf(v, v, ss);
        _Float16 hi = (_Float16)v;
        h[j] = hi;
        lo[j] = (_Float16)(v - (float)hi);
    }
    ehi[t] = h;
    elo[t] = lo;
    part[tid] = ss;
    __syncthreads();
    if (tid < 32) {
        float a = 0.f;
#pragma unroll
        for (int q = 0; q < 8; ++q)
            a += part[tid + 32 * (q & 1) + 64 * (q >> 1)];
        sq[c * 32 + tid] = a;
    }
}

// ---------------------------------------------------------------------------
// Kernel 1: fully fused dist(GEMM 32x32x16) + argmax + combine + gather,
// with REGISTER DOUBLE-BUFFERED B (prefetch tile c+1 during tile c's MFMAs
// -> loads stay in flight across the compute block, fine-grained vmcnt).
// Block = 4 waves over the SAME 64 rows; wave w sweeps tiles [w*32,(w+1)*32).
// dist = dot(2x,e) - ||e||^2 ; -||e||^2 = acc init, 2x folded into A (exact).
// fp16 split, 3 terms: xh*eh + xl*eh + xh*el.
// grid = 512 blocks (= 2 blocks/CU, 2 waves/SIMD), block = 256.
// ---------------------------------------------------------------------------
#define LOADTILE(buf, c)                                                     \
    {                                                                        \
        const int cc = (c);                                                  \
        const half8* p = ehi + (size_t)(c0 + cc) * 256 + lane;               \
        bh##buf[0] = p[0];                                                   \
        bh##buf[1] = p[64];                                                  \
        bh##buf[2] = p[128];                                                 \
        bh##buf[3] = p[192];                                                 \
        const half8* q = elo + (size_t)(c0 + cc) * 256 + lane;               \
        bl##buf[0] = q[0];                                                   \
        bl##buf[1] = q[64];                                                  \
        bl##buf[2] = q[128];                                                 \
        bl##buf[3] = q[192];                                                 \
        nsq##buf = -sq[(size_t)(c0 + cc) * 32 + col];                        \
    }

#define COMPUTETILE(buf, c)                                                  \
    {                                                                        \
        floatx16 acc0, acc1;                                                 \
        _Pragma("unroll") for (int r = 0; r < 16; ++r) {                     \
            acc0[r] = nsq##buf;                                              \
            acc1[r] = nsq##buf;                                              \
        }                                                                    \
        _Pragma("unroll") for (int s = 0; s < 4; ++s) {                      \
            acc0 = MFMA32(ah[0][s], bh##buf[s], acc0);                       \
            acc1 = MFMA32(ah[1][s], bh##buf[s], acc1);                       \
            acc0 = MFMA32(al[0][s], bh##buf[s], acc0);                       \
            acc1 = MFMA32(al[1][s], bh##buf[s], acc1);                       \
            acc0 = MFMA32(ah[0][s], bl##buf[s], acc0);                       \
            acc1 = MFMA32(ah[1][s], bl##buf[s], acc1);                       \
        }                                                                    \
        const int cidx = (c0 + (c)) * 32 + col;                              \
        _Pragma("unroll") for (int r = 0; r < 16; ++r) {                     \
            if (acc0[r] > best0[r]) { /* strict >: earliest wins ties */     \
                best0[r] = acc0[r];                                          \
                idx0[r] = cidx;                                              \
            }                                                                \
            if (acc1[r] > best1[r]) {                                        \
                best1[r] = acc1[r];                                          \
                idx1[r] = cidx;                                              \
            }                                                                \
        }                                                                    \
    }

__global__ __launch_bounds__(256, 2) void fused_all(
    const float* __restrict__ x, const float* __restrict__ sq,
    const half8* __restrict__ ehi, const half8* __restrict__ elo,
    const float* __restrict__ embed, float* __restrict__ out) {
    __shared__ float rbest[4][64];
    __shared__ int ridx[4][64];
    __shared__ int fidx[64];

    const int tid = threadIdx.x;
    const int lane = tid & 63;
    const int wave = tid >> 6;
    const int col = lane & 31;    // B col (code within tile); A row
    const int half_ = lane >> 5;  // k-half
    const int row_base = blockIdx.x * 64;

    // Persistent A fragments, two 32-row subtiles, scaled by 2 (exact).
    // A[m=col (+32*m)][k = half_*8 + j + 16*s]
    half8 ah[2][4], al[2][4];
#pragma unroll
    for (int m = 0; m < 2; ++m) {
        const float* xs =
            x + (size_t)(row_base + m * 32 + col) * DIM + half_ * 8;
#pragma unroll
        for (int s = 0; s < 4; ++s) {
            half8 h, lo;
#pragma unroll
            for (int j = 0; j < 8; ++j) {
                float v = 2.0f * xs[16 * s + j];
                _Float16 hi = (_Float16)v;
                h[j] = hi;
                lo[j] = (_Float16)(v - (float)hi);
            }
            ah[m][s] = h;
            al[m][s] = lo;
        }
    }

    float best0[16], best1[16];
    int idx0[16], idx1[16];
#pragma unroll
    for (int r = 0; r < 16; ++r) {
        best0[r] = -INFINITY;
        best1[r] = -INFINITY;
        idx0[r] = 0;
        idx1[r] = 0;
    }

    const int c0 = wave * TILES_PER_WAVE;
    half8 bh0[4], bl0[4], bh1[4], bl1[4];
    float nsq0, nsq1;

    LOADTILE(0, 0)
    // Pipelined sweep: load (c+1) while computing c. Ascending c order is
    // preserved, so tie-break (strict >) still matches jnp.argmax.
    for (int c = 0; c < TILES_PER_WAVE; c += 2) {
        LOADTILE(1, c + 1)
        COMPUTETILE(0, c)
        LOADTILE(0, c + 2 < TILES_PER_WAVE ? c + 2 : TILES_PER_WAVE - 1)
        COMPUTETILE(1, c + 1)
    }

    // C/D layout (32x32): col = lane&31, row = (r&3) + 8*(r>>2) + 4*half_.
    // Butterfly over the 32 lanes of each half (cols), stash per-wave winners.
#pragma unroll
    for (int r = 0; r < 16; ++r) {
        const int row = (r & 3) + 8 * (r >> 2) + 4 * half_;
        float bv = best0[r];
        int bi = idx0[r];
#pragma unroll
        for (int d = 1; d < 32; d <<= 1) {
            float ov = __shfl_xor(bv, d);
            int oi = __shfl_xor(bi, d);
            if (ov > bv || (ov == bv && oi < bi)) {  // smaller idx on tie
                bv = ov;
                bi = oi;
            }
        }
        if (col == 0) {
            rbest[wave][row] = bv;
            ridx[wave][row] = bi;
        }
        bv = best1[r];
        bi = idx1[r];
#pragma unroll
        for (int d = 1; d < 32; d <<= 1) {
            float ov = __shfl_xor(bv, d);
            int oi = __shfl_xor(bi, d);
            if (ov > bv || (ov == bv && oi < bi)) {
                bv = ov;
                bi = oi;
            }
        }
        if (col == 0) {
            rbest[wave][row + 32] = bv;
            ridx[wave][row + 32] = bi;
        }
    }
    __syncthreads();

    // Cross-wave combine: wave order == ascending code ranges, so strict >
    // preserves jnp.argmax first-max semantics.
    if (tid < 64) {
        float bv = rbest[0][tid];
        int bi = ridx[0][tid];
#pragma unroll
        for (int w = 1; w < 4; ++w) {
            float b = rbest[w][tid];
            if (b > bv) {
                bv = b;
                bi = ridx[w][tid];
            }
        }
        fidx[tid] = bi;
        out[(size_t)QUANT_ELEMS + row_base + tid] = (float)bi;
    }
    __syncthreads();

    // Gather + write quantize: 256 threads x 4 float4 chunks = 64 rows x 64f.
    const int grow = tid >> 2;
    const int q0 = tid & 3;
    const int bi = fidx[grow];
    const float4* e4 = reinterpret_cast<const float4*>(embed);
    float4* o4 = reinterpret_cast<float4*>(out);
#pragma unroll
    for (int q = 0; q < 4; ++q) {
        const int chunk = q0 + 4 * q;
        o4[(size_t)(row_base + grow) * (DIM / 4) + chunk] =
            e4[(size_t)bi * (DIM / 4) + chunk];
    }
}

// ---------------------------------------------------------------------------
extern "C" void kernel_launch(void* const* d_in, const int* in_sizes, int n_in,
                              void* d_out, int out_size, void* d_ws,
                              size_t ws_size, hipStream_t stream) {
    const float* x = (const float*)d_in[0];
    const float* embed = (const float*)d_in[1];
    float* out = (float*)d_out;

    // ws: sq 16KB | ehi 512KB | elo 512KB
    char* ws = (char*)d_ws;
    float* sq = (float*)ws;
    half8* ehi = (half8*)(ws + 16384);
    half8* elo = (half8*)(ws + 16384 + 524288);

    prep_kernel<<<TILES_TOTAL, 256, 0, stream>>>(embed, sq, ehi, elo);

    fused_all<<<N_ROWS / 64, 256, 0, stream>>>(x, sq, ehi, elo, embed, out);
}